// Round 4
// baseline (2148.265 us; speedup 1.0000x reference)
//
// MoCA fused pipeline — round 4: ws-safe layout (224MiB fixed + <=33.5MB strip),
// fused conv_g+transpose, F-buffer reuse, K-concat split-bf16 MFMA GEMMs.
#include <hip/hip_runtime.h>

#define Bz 8
#define Sz 2048
#define Dz 1024

typedef __attribute__((ext_vector_type(8))) short bf16x8;
typedef __attribute__((ext_vector_type(4))) short short4v;
typedef __attribute__((ext_vector_type(4))) float f32x4;

__device__ __forceinline__ short f2b(float f) {          // round-to-nearest-even bf16
    unsigned u = __float_as_uint(f);
    return (short)((u + 0x7fffu + ((u >> 16) & 1u)) >> 16);
}
__device__ __forceinline__ float b2f(short s) {
    return __uint_as_float(((unsigned)(unsigned short)s) << 16);
}
// hi = truncated bf16, lo = rounded residual
__device__ __forceinline__ void split1(float f, short& h, short& l) {
    unsigned u = __float_as_uint(f);
    h = (short)(u >> 16);
    l = f2b(f - __uint_as_float(u & 0xffff0000u));
}
__device__ __forceinline__ void gld16(const void* g, void* l) {
    __builtin_amdgcn_global_load_lds(
        (const __attribute__((address_space(1))) void*)g,
        (__attribute__((address_space(3))) void*)l, 16, 0, 0);
}

// ---------------- fused 5x5 convs over x (4 rows/block) ----------------
// emits split conv_x (C1h/C1l), split conv_xT-as-[s,d] (C2h/C2l), split x (xh/xl)
__global__ __launch_bounds__(256) void conv3_kernel(
    const float* __restrict__ x,
    const float* __restrict__ w1, const float* __restrict__ b1,
    const float* __restrict__ w2, const float* __restrict__ b2,
    short* __restrict__ C1h, short* __restrict__ C1l,
    short* __restrict__ C2h, short* __restrict__ C2l,
    short* __restrict__ xh, short* __restrict__ xl)
{
    __shared__ float xs[8][1032];
    __shared__ float w[50];
    __shared__ float bias[2];
    const size_t SD = (size_t)Sz * Dz;
    int tid = threadIdx.x;
    if (tid < 25) w[tid] = w1[tid];
    else if (tid < 50) w[tid] = w2[tid - 25];
    if (tid == 50) { bias[0] = b1[0]; bias[1] = b2[0]; }

    int s0 = blockIdx.y * 4, b = blockIdx.z;
    const float* xb = x + (size_t)b * SD;
#pragma unroll
    for (int i = 0; i < 8; i++) {
        int ss = s0 + i - 2;
        float4 v = make_float4(0.f, 0.f, 0.f, 0.f);
        if (ss >= 0 && ss < Sz) v = *(const float4*)(xb + (size_t)ss * Dz + tid * 4);
        *(float4*)&xs[i][4 + tid * 4] = v;
    }
    if (tid < 32) { int r = tid >> 2, c = tid & 3; xs[r][(c < 2) ? (2 + c) : (1026 + c)] = 0.f; }
    __syncthreads();

    int d = tid * 4;
#pragma unroll
    for (int r = 0; r < 4; r++) {
        float o1[4] = {}, o2[4] = {}, xv[4];
#pragma unroll
        for (int i = 0; i < 5; i++) {
            float wv[12];
            *(float4*)&wv[0] = *(float4*)&xs[r + i][d];
            *(float4*)&wv[4] = *(float4*)&xs[r + i][d + 4];
            *(float4*)&wv[8] = *(float4*)&xs[r + i][d + 8];
            if (i == 2) { xv[0] = wv[4]; xv[1] = wv[5]; xv[2] = wv[6]; xv[3] = wv[7]; }
#pragma unroll
            for (int j = 0; j < 5; j++) {
                float c1w = w[i * 5 + j], c2w = w[25 + j * 5 + i];
#pragma unroll
                for (int q = 0; q < 4; q++) {
                    float v = wv[q + j + 2];
                    o1[q] = fmaf(c1w, v, o1[q]);
                    o2[q] = fmaf(c2w, v, o2[q]);
                }
            }
        }
        size_t o = (size_t)b * SD + (size_t)(s0 + r) * Dz + d;
        short4v h1, l1, h2, l2, hx, lx;
#pragma unroll
        for (int q = 0; q < 4; q++) {
            short hh, ll;
            split1(o1[q] + bias[0], hh, ll); h1[q] = hh; l1[q] = ll;
            split1(o2[q] + bias[1], hh, ll); h2[q] = hh; l2[q] = ll;
            split1(xv[q], hh, ll); hx[q] = hh; lx[q] = ll;
        }
        *(short4v*)(C1h + o) = h1; *(short4v*)(C1l + o) = l1;
        *(short4v*)(C2h + o) = h2; *(short4v*)(C2l + o) = l2;
        *(short4v*)(xh + o) = hx;  *(short4v*)(xl + o) = lx;
    }
}

// ---------------- fused conv_g (5x5) + transpose: x[s,d] -> C4T[d,s] bf16 ----------------
__global__ __launch_bounds__(256) void convT_kernel(
    const float* __restrict__ x, const float* __restrict__ w4,
    const float* __restrict__ b4, short* __restrict__ C4T)
{
    __shared__ float xs[68][73];
    __shared__ short ct[64][72];
    __shared__ float w[25];
    __shared__ float bb;
    const size_t SD = (size_t)Sz * Dz;
    int tid = threadIdx.x;
    if (tid < 25) w[tid] = w4[tid];
    if (tid == 25) bb = b4[0];

    int s0 = blockIdx.x * 64, d0 = blockIdx.y * 64, b = blockIdx.z;
    const float* xb = x + (size_t)b * SD;
    for (int k = tid; k < 68 * 68; k += 256) {
        int r = k / 68, c = k - r * 68;
        int gr = s0 - 2 + r, gc = d0 - 2 + c;
        float v = 0.f;
        if (gr >= 0 && gr < Sz && gc >= 0 && gc < Dz) v = xb[(size_t)gr * Dz + gc];
        xs[r][c] = v;
    }
    __syncthreads();

    int sl = tid & 63, dg = tid >> 6;          // 64 s-rows x 4 d-groups of 16
    float acc[16];
#pragma unroll
    for (int q = 0; q < 16; q++) acc[q] = bb;
#pragma unroll
    for (int i = 0; i < 5; i++) {
        float row[20];
#pragma unroll
        for (int m = 0; m < 20; m++) row[m] = xs[sl + i][dg * 16 + m];
#pragma unroll
        for (int j = 0; j < 5; j++) {
            float wv = w[i * 5 + j];
#pragma unroll
            for (int q = 0; q < 16; q++) acc[q] = fmaf(wv, row[q + j], acc[q]);
        }
    }
#pragma unroll
    for (int q = 0; q < 16; q++) ct[dg * 16 + q][sl] = f2b(acc[q]);
    __syncthreads();

    int dl = tid >> 2, sc = (tid & 3) * 16;
    bf16x8 v0 = *(const bf16x8*)&ct[dl][sc];
    bf16x8 v1 = *(const bf16x8*)&ct[dl][sc + 8];
    short* op = C4T + (size_t)b * SD + (size_t)(d0 + dl) * Sz + s0 + sc;
    *(bf16x8*)op = v0;
    *(bf16x8*)(op + 8) = v1;
}

// ---------------- bf16 MFMA NT GEMM, m97 structure ----------------
// C[m,n] = sum over phases A_ph[m,:]·B_ph[n,:]  (+Src if ADD)
// NPH=3: phases (Ah,Bh),(Al,Bh),(Ah,Bl) == split-fp32 product.
// 128x128 tile, BK=64, 4 waves (2x2), global_load_lds + both-sides XOR swizzle.
template <int NPH, bool ADD>
__global__ __launch_bounds__(256) void gemm_bt(
    const short* __restrict__ Ah, const short* __restrict__ Al,
    const short* __restrict__ Bh, const short* __restrict__ Bl,
    const float* __restrict__ Src, float* __restrict__ C,
    int M, int N, int K,
    long sAb, long sBb, long sCb, long sSb)
{
    __shared__ short ldsA[128 * 64];
    __shared__ short ldsB[128 * 64];

    const int bz = blockIdx.z;
    Ah += (size_t)bz * sAb; Bh += (size_t)bz * sBb;
    if (NPH == 3) { Al += (size_t)bz * sAb; Bl += (size_t)bz * sBb; }
    C += (size_t)bz * sCb;
    if (ADD) Src += (size_t)bz * sSb;

    const int m0 = blockIdx.y * 128, n0 = blockIdx.x * 128;
    const int t = threadIdx.x;
    const int lane = t & 63;
    const int w = t >> 6;
    const int wm = w >> 1, wn = w & 1;
    const int fr = lane & 15;
    const int kb = lane >> 4;
    const int swz = (fr & 7) << 4;       // read-side XOR: (row&7)<<4 bytes

    const int sr_ = t >> 3;              // staging row within 32-row chunk
    const int scb = (t & 7) * 16;        // staging col byte

    f32x4 acc[4][4];
#pragma unroll
    for (int i = 0; i < 4; i++)
#pragma unroll
        for (int j = 0; j < 4; j++) acc[i][j] = (f32x4){0.f, 0.f, 0.f, 0.f};

    for (int ph = 0; ph < NPH; ph++) {
        const short* As = (NPH == 3 && ph == 1) ? Al : Ah;
        const short* Bs = (NPH == 3 && ph == 2) ? Bl : Bh;
        for (int k0 = 0; k0 < K; k0 += 64) {
            __syncthreads();             // previous tile fully consumed
#pragma unroll
            for (int c = 0; c < 4; c++) {
                int r = c * 32 + sr_;
                int row = m0 + r; if (row > M - 1) row = M - 1;
                int cb = scb ^ ((r & 7) << 4);   // inverse-swizzled SOURCE col
                gld16((const char*)As + ((size_t)row * K + k0) * 2 + cb,
                      (char*)ldsA + c * 4096 + t * 16);
            }
#pragma unroll
            for (int c = 0; c < 4; c++) {
                int r = c * 32 + sr_;
                int cb = scb ^ ((r & 7) << 4);
                gld16((const char*)Bs + ((size_t)(n0 + r) * K + k0) * 2 + cb,
                      (char*)ldsB + c * 4096 + t * 16);
            }
            __syncthreads();             // drain + barrier: tile ready
#pragma unroll
            for (int ks = 0; ks < 2; ks++) {
                bf16x8 af[4], bf_[4];
#pragma unroll
                for (int f = 0; f < 4; f++) {
                    int rowA = wm * 64 + f * 16 + fr;
                    af[f] = *(const bf16x8*)((const char*)ldsA + rowA * 128 + ((ks * 64 + kb * 16) ^ swz));
                    int rowB = wn * 64 + f * 16 + fr;
                    bf_[f] = *(const bf16x8*)((const char*)ldsB + rowB * 128 + ((ks * 64 + kb * 16) ^ swz));
                }
#pragma unroll
                for (int mf = 0; mf < 4; mf++)
#pragma unroll
                    for (int nf = 0; nf < 4; nf++)
                        acc[mf][nf] = __builtin_amdgcn_mfma_f32_16x16x32_bf16(af[mf], bf_[nf], acc[mf][nf], 0, 0, 0);
            }
        }
    }

#pragma unroll
    for (int mf = 0; mf < 4; mf++)
#pragma unroll
        for (int nf = 0; nf < 4; nf++) {
            int col = n0 + wn * 64 + nf * 16 + fr;
#pragma unroll
            for (int r = 0; r < 4; r++) {
                int rowg = m0 + wm * 64 + mf * 16 + kb * 4 + r;
                if (rowg < M) {
                    float o = acc[mf][nf][r];
                    if (ADD) o += Src[(size_t)rowg * N + col];
                    C[(size_t)rowg * N + col] = o;
                }
            }
        }
}

// ---------------- softmax over batch dim (8 planes), fp32 in -> bf16 out ----------------
__global__ __launch_bounds__(256) void softmax_bf(
    const float* __restrict__ P, short* __restrict__ Q, int nElem, long ps)
{
    int i4 = (blockIdx.x * 256 + threadIdx.x) * 4;
    if (i4 >= nElem) return;
    float4 v[Bz];
    float4 mx = make_float4(-1e30f, -1e30f, -1e30f, -1e30f);
#pragma unroll
    for (int b = 0; b < Bz; b++) {
        v[b] = *(const float4*)(P + i4 + (size_t)b * ps);
        mx.x = fmaxf(mx.x, v[b].x); mx.y = fmaxf(mx.y, v[b].y);
        mx.z = fmaxf(mx.z, v[b].z); mx.w = fmaxf(mx.w, v[b].w);
    }
    float4 sum = make_float4(0.f, 0.f, 0.f, 0.f);
#pragma unroll
    for (int b = 0; b < Bz; b++) {
        v[b].x = __expf(v[b].x - mx.x); v[b].y = __expf(v[b].y - mx.y);
        v[b].z = __expf(v[b].z - mx.z); v[b].w = __expf(v[b].w - mx.w);
        sum.x += v[b].x; sum.y += v[b].y; sum.z += v[b].z; sum.w += v[b].w;
    }
    float4 inv = make_float4(1.f / sum.x, 1.f / sum.y, 1.f / sum.z, 1.f / sum.w);
#pragma unroll
    for (int b = 0; b < Bz; b++) {
        short4v r;
        r[0] = f2b(v[b].x * inv.x); r[1] = f2b(v[b].y * inv.y);
        r[2] = f2b(v[b].z * inv.z); r[3] = f2b(v[b].w * inv.w);
        *(short4v*)(Q + i4 + (size_t)b * ps) = r;
    }
}

// ---------------- moca 5x5 conv over bf16 {G_sm, A_sm} -> bf16 M ----------------
__global__ __launch_bounds__(256) void moca_kernel(
    const short* __restrict__ Gs, const short* __restrict__ As,
    const float* __restrict__ w3, const float* __restrict__ b3,
    short* __restrict__ Mout,
    int s0, int rlo, long psIn, long psOut)
{
    __shared__ float w[50];
    __shared__ float bb;
    int tid = threadIdx.x;
    if (tid < 50) w[tid] = w3[tid];
    if (tid == 50) bb = b3[0];
    __syncthreads();

    int t8 = tid * 8;
    int so = blockIdx.y, b = blockIdx.z;
    int s = s0 + so;
    const short* Gp = Gs + (size_t)b * psIn;
    const short* Ap = As + (size_t)b * psIn;

    float acc[8];
#pragma unroll
    for (int q = 0; q < 8; q++) acc[q] = bb;

#pragma unroll
    for (int i = 0; i < 5; i++) {
        int sr = s + i - 2;
        if (sr < 0 || sr >= Sz) continue;
        size_t ro = (size_t)(sr - rlo) * Sz;
        float gw[16], aw[16];
#pragma unroll
        for (int g = 0; g < 4; g++) {
            int c0 = t8 - 4 + g * 4;
            if (c0 >= 0 && c0 + 3 < Sz) {
                short4v gv = *(const short4v*)(Gp + ro + c0);
                short4v av = *(const short4v*)(Ap + ro + c0);
#pragma unroll
                for (int e = 0; e < 4; e++) { gw[g * 4 + e] = b2f(gv[e]); aw[g * 4 + e] = b2f(av[e]); }
            } else {
#pragma unroll
                for (int e = 0; e < 4; e++) { gw[g * 4 + e] = 0.f; aw[g * 4 + e] = 0.f; }
            }
        }
#pragma unroll
        for (int j = 0; j < 5; j++) {
            float wg = w[i * 5 + j], wa = w[25 + i * 5 + j];
#pragma unroll
            for (int q = 0; q < 8; q++)
                acc[q] = fmaf(wg, gw[q + j + 2], fmaf(wa, aw[q + j + 2], acc[q]));
        }
    }
    bf16x8 r;
#pragma unroll
    for (int q = 0; q < 8; q++) r[q] = f2b(acc[q]);
    *(bf16x8*)(Mout + (size_t)b * psOut + (size_t)so * Sz + t8) = r;
}

// ---------------- host ----------------
extern "C" void kernel_launch(void* const* d_in, const int* in_sizes, int n_in,
                              void* d_out, int out_size, void* d_ws, size_t ws_size,
                              hipStream_t stream)
{
    const float* x  = (const float*)d_in[0];
    const float* w1 = (const float*)d_in[1];
    const float* b1 = (const float*)d_in[2];
    const float* w2 = (const float*)d_in[3];
    const float* b2 = (const float*)d_in[4];
    const float* w3 = (const float*)d_in[5];
    const float* b3 = (const float*)d_in[6];
    const float* w4 = (const float*)d_in[7];
    const float* b4 = (const float*)d_in[8];
    float* out = (float*)d_out;

    const size_t SD = (size_t)Sz * Dz;
    const size_t BSD2 = (size_t)Bz * SD * 2;     // 32MiB per bf16 [B,S,D] buffer

    char* ws = (char*)d_ws;
    short* xh  = (short*)(ws);
    short* xl  = (short*)(ws + 1 * BSD2);
    short* C1h = (short*)(ws + 2 * BSD2);
    short* C1l = (short*)(ws + 3 * BSD2);
    short* C2h = (short*)(ws + 4 * BSD2);
    short* C2l = (short*)(ws + 5 * BSD2);
    short* C4T = (short*)(ws + 6 * BSD2);
    char* strip0 = ws + 7 * BSD2;                // 224MiB fixed

    // strip region: F fp32 (reused G/A logits, later aliased by Mb) + Gsm + Asm bf16
    const int hs[4] = { 508, 252, 124, 60 };
    int h = 60;
    for (int i = 0; i < 4; i++) {
        size_t need = 7 * BSD2 + (size_t)131072 * (hs[i] + 4);  // Bz*PS*(4+2+2)
        if (need <= ws_size) { h = hs[i]; break; }
    }
    const size_t PS  = (size_t)(h + 4) * Sz;     // elems/plane for F/Gsm/Asm
    const size_t PSM = (size_t)h * Sz;           // elems/plane for M
    float* F   = (float*)strip0;
    short* Gsm = (short*)(F + (size_t)Bz * PS);
    short* Asm = Gsm + (size_t)Bz * PS;
    short* Mb  = (short*)strip0;                 // aliases F (free after softmaxes)

    conv3_kernel<<<dim3(1, Sz / 4, Bz), 256, 0, stream>>>(
        x, w1, b1, w2, b2, C1h, C1l, C2h, C2l, xh, xl);
    convT_kernel<<<dim3(Sz / 64, Dz / 64, Bz), 256, 0, stream>>>(x, w4, b4, C4T);

    for (int s0 = 0; s0 < Sz; s0 += h) {
        int hcur = (Sz - s0 < h) ? (Sz - s0) : h;
        int rlo = s0 - 2; if (rlo < 0) rlo = 0;
        int rhi = s0 + hcur + 2; if (rhi > Sz) rhi = Sz;
        int nv = rhi - rlo;
        int ne = nv * Sz;
        dim3 g1(Sz / 128, (nv + 127) / 128, Bz);

        // G logits -> F -> softmax -> Gsm
        gemm_bt<3, false><<<g1, 256, 0, stream>>>(
            xh + (size_t)rlo * Dz, xl + (size_t)rlo * Dz, xh, xl,
            nullptr, F, nv, Sz, Dz, (long)SD, (long)SD, (long)PS, 0);
        softmax_bf<<<(ne / 4 + 255) / 256, 256, 0, stream>>>(F, Gsm, ne, (long)PS);

        // A logits -> F (reuse) -> softmax -> Asm
        gemm_bt<3, false><<<g1, 256, 0, stream>>>(
            C1h + (size_t)rlo * Dz, C1l + (size_t)rlo * Dz, C2h, C2l,
            nullptr, F, nv, Sz, Dz, (long)SD, (long)SD, (long)PS, 0);
        softmax_bf<<<(ne / 4 + 255) / 256, 256, 0, stream>>>(F, Asm, ne, (long)PS);

        // moca -> Mb (aliases F)
        moca_kernel<<<dim3(1, hcur, Bz), 256, 0, stream>>>(
            Gsm, Asm, w3, b3, Mb, s0, rlo, (long)PS, (long)PSM);

        // Wz = M @ C4T^T + x -> out
        dim3 g2(Dz / 128, (hcur + 127) / 128, Bz);
        gemm_bt<1, true><<<g2, 256, 0, stream>>>(
            Mb, Mb, C4T, C4T,
            x + (size_t)s0 * Dz, out + (size_t)s0 * Dz,
            hcur, Dz, Sz, (long)PSM, (long)SD, (long)SD, (long)SD);
    }
}

// Round 5
// 929.149 us; speedup vs baseline: 2.3121x; 2.3121x over previous
//
// MoCA fused pipeline — round 5: single-pass fp16 MFMA GEMMs (replaces 3-phase
// split-bf16), fp16 operands/probs/M everywhere, big strips (h=512..1024),
// round-2-proven conv3 structure. Fixed buffers 128MiB + strip <=135MB.
#include <hip/hip_runtime.h>

#define Bz 8
#define Sz 2048
#define Dz 1024

typedef __attribute__((ext_vector_type(8))) _Float16 f16x8;
typedef __attribute__((ext_vector_type(4))) short short4v;
typedef __attribute__((ext_vector_type(4))) float f32x4;

__device__ __forceinline__ short f2h(float f) {
    _Float16 h = (_Float16)f;
    return __builtin_bit_cast(short, h);
}
__device__ __forceinline__ float h2f(short s) {
    return (float)__builtin_bit_cast(_Float16, s);
}
__device__ __forceinline__ void gld16(const void* g, void* l) {
    __builtin_amdgcn_global_load_lds(
        (const __attribute__((address_space(1))) void*)g,
        (__attribute__((address_space(3))) void*)l, 16, 0, 0);
}

// ---------------- fused 5x5 convs over x (1 row/block, round-2 structure) ----------------
// emits fp16: x16[s,d], C1f[s,d]=conv(w1), C2f[s,d]=conv(w2^T) (== conv_xT as [s,d])
__global__ __launch_bounds__(256) void conv3_kernel(
    const float* __restrict__ x,
    const float* __restrict__ w1, const float* __restrict__ b1,
    const float* __restrict__ w2, const float* __restrict__ b2,
    short* __restrict__ x16, short* __restrict__ C1f, short* __restrict__ C2f)
{
    __shared__ float xs[5][1032];
    __shared__ float w[50];
    __shared__ float bias[2];
    const size_t SD = (size_t)Sz * Dz;
    int tid = threadIdx.x;
    if (tid < 25) w[tid] = w1[tid];
    else if (tid < 50) w[tid] = w2[tid - 25];
    if (tid == 50) { bias[0] = b1[0]; bias[1] = b2[0]; }

    int s = blockIdx.y, b = blockIdx.z;
    const float* xb = x + (size_t)b * SD;
#pragma unroll
    for (int i = 0; i < 5; i++) {
        int ss = s + i - 2;
        float4 v = make_float4(0.f, 0.f, 0.f, 0.f);
        if (ss >= 0 && ss < Sz) v = *(const float4*)(xb + (size_t)ss * Dz + tid * 4);
        *(float4*)&xs[i][4 + tid * 4] = v;
    }
    if (tid < 20) { int r = tid >> 2, c = tid & 3; xs[r][(c < 2) ? (2 + c) : (1026 + c)] = 0.f; }
    __syncthreads();

    int d = tid * 4;
    float o1[4] = {}, o2[4] = {}, xv[4];
#pragma unroll
    for (int i = 0; i < 5; i++) {
        float wv[12];
        *(float4*)&wv[0] = *(float4*)&xs[i][d];
        *(float4*)&wv[4] = *(float4*)&xs[i][d + 4];
        *(float4*)&wv[8] = *(float4*)&xs[i][d + 8];
        if (i == 2) { xv[0] = wv[4]; xv[1] = wv[5]; xv[2] = wv[6]; xv[3] = wv[7]; }
#pragma unroll
        for (int j = 0; j < 5; j++) {
            float c1w = w[i * 5 + j], c2w = w[25 + j * 5 + i];
#pragma unroll
            for (int q = 0; q < 4; q++) {
                float v = wv[q + j + 2];
                o1[q] = fmaf(c1w, v, o1[q]);
                o2[q] = fmaf(c2w, v, o2[q]);
            }
        }
    }
    size_t o = (size_t)b * SD + (size_t)s * Dz + d;
    short4v hx, h1, h2;
#pragma unroll
    for (int q = 0; q < 4; q++) {
        hx[q] = f2h(xv[q]);
        h1[q] = f2h(o1[q] + bias[0]);
        h2[q] = f2h(o2[q] + bias[1]);
    }
    *(short4v*)(x16 + o) = hx;
    *(short4v*)(C1f + o) = h1;
    *(short4v*)(C2f + o) = h2;
}

// ---------------- fused conv_g (5x5) + transpose: x[s,d] -> C4T[d,s] fp16 ----------------
__global__ __launch_bounds__(256) void convT_kernel(
    const float* __restrict__ x, const float* __restrict__ w4,
    const float* __restrict__ b4, short* __restrict__ C4T)
{
    __shared__ float xs[68][73];
    __shared__ short ct[64][72];
    __shared__ float w[25];
    __shared__ float bb;
    const size_t SD = (size_t)Sz * Dz;
    int tid = threadIdx.x;
    if (tid < 25) w[tid] = w4[tid];
    if (tid == 25) bb = b4[0];

    int s0 = blockIdx.x * 64, d0 = blockIdx.y * 64, b = blockIdx.z;
    const float* xb = x + (size_t)b * SD;
    for (int k = tid; k < 68 * 68; k += 256) {
        int r = k / 68, c = k - r * 68;
        int gr = s0 - 2 + r, gc = d0 - 2 + c;
        float v = 0.f;
        if (gr >= 0 && gr < Sz && gc >= 0 && gc < Dz) v = xb[(size_t)gr * Dz + gc];
        xs[r][c] = v;
    }
    __syncthreads();

    int sl = tid & 63, dg = tid >> 6;          // 64 s-rows x 4 d-groups of 16
    float acc[16];
#pragma unroll
    for (int q = 0; q < 16; q++) acc[q] = bb;
#pragma unroll
    for (int i = 0; i < 5; i++) {
        float row[20];
#pragma unroll
        for (int m = 0; m < 20; m++) row[m] = xs[sl + i][dg * 16 + m];
#pragma unroll
        for (int j = 0; j < 5; j++) {
            float wv = w[i * 5 + j];
#pragma unroll
            for (int q = 0; q < 16; q++) acc[q] = fmaf(wv, row[q + j], acc[q]);
        }
    }
#pragma unroll
    for (int q = 0; q < 16; q++) ct[dg * 16 + q][sl] = f2h(acc[q]);
    __syncthreads();

    int dl = tid >> 2, sc = (tid & 3) * 16;
    f16x8 v0 = *(const f16x8*)&ct[dl][sc];
    f16x8 v1 = *(const f16x8*)&ct[dl][sc + 8];
    short* op = C4T + (size_t)b * SD + (size_t)(d0 + dl) * Sz + s0 + sc;
    *(f16x8*)op = v0;
    *(f16x8*)(op + 8) = v1;
}

// ---------------- fp16 MFMA NT GEMM, m97 structure ----------------
// C[m,n] = A[m,:]·B[n,:] (+Src[m,n] if ADD), fp32 out.
// 128x128 tile, BK=64, 4 waves (2x2), global_load_lds + both-sides XOR swizzle.
template <bool ADD>
__global__ __launch_bounds__(256) void gemm_f16(
    const short* __restrict__ A, const short* __restrict__ B,
    const float* __restrict__ Src, float* __restrict__ C,
    int M, int N, int K,
    long sAb, long sBb, long sCb, long sSb)
{
    __shared__ short ldsA[128 * 64];
    __shared__ short ldsB[128 * 64];

    const int bz = blockIdx.z;
    A += (size_t)bz * sAb; B += (size_t)bz * sBb;
    C += (size_t)bz * sCb;
    if (ADD) Src += (size_t)bz * sSb;

    const int m0 = blockIdx.y * 128, n0 = blockIdx.x * 128;
    const int t = threadIdx.x;
    const int lane = t & 63;
    const int w = t >> 6;
    const int wm = w >> 1, wn = w & 1;
    const int fr = lane & 15;
    const int kb = lane >> 4;
    const int swz = (fr & 7) << 4;       // read-side XOR: (row&7)<<4 bytes

    const int sr_ = t >> 3;              // staging row within 32-row chunk
    const int scb = (t & 7) * 16;        // staging col byte

    f32x4 acc[4][4];
#pragma unroll
    for (int i = 0; i < 4; i++)
#pragma unroll
        for (int j = 0; j < 4; j++) acc[i][j] = (f32x4){0.f, 0.f, 0.f, 0.f};

    for (int k0 = 0; k0 < K; k0 += 64) {
        __syncthreads();                 // previous tile fully consumed
#pragma unroll
        for (int c = 0; c < 4; c++) {
            int r = c * 32 + sr_;
            int row = m0 + r; if (row > M - 1) row = M - 1;
            int cb = scb ^ ((r & 7) << 4);   // inverse-swizzled SOURCE col
            gld16((const char*)A + ((size_t)row * K + k0) * 2 + cb,
                  (char*)ldsA + c * 4096 + t * 16);
        }
#pragma unroll
        for (int c = 0; c < 4; c++) {
            int r = c * 32 + sr_;
            int cb = scb ^ ((r & 7) << 4);
            gld16((const char*)B + ((size_t)(n0 + r) * K + k0) * 2 + cb,
                  (char*)ldsB + c * 4096 + t * 16);
        }
        __syncthreads();                 // drain + barrier: tile ready
#pragma unroll
        for (int ks = 0; ks < 2; ks++) {
            f16x8 af[4], bf_[4];
#pragma unroll
            for (int f = 0; f < 4; f++) {
                int rowA = wm * 64 + f * 16 + fr;
                af[f] = *(const f16x8*)((const char*)ldsA + rowA * 128 + ((ks * 64 + kb * 16) ^ swz));
                int rowB = wn * 64 + f * 16 + fr;
                bf_[f] = *(const f16x8*)((const char*)ldsB + rowB * 128 + ((ks * 64 + kb * 16) ^ swz));
            }
#pragma unroll
            for (int mf = 0; mf < 4; mf++)
#pragma unroll
                for (int nf = 0; nf < 4; nf++)
                    acc[mf][nf] = __builtin_amdgcn_mfma_f32_16x16x32_f16(af[mf], bf_[nf], acc[mf][nf], 0, 0, 0);
        }
    }

#pragma unroll
    for (int mf = 0; mf < 4; mf++)
#pragma unroll
        for (int nf = 0; nf < 4; nf++) {
            int col = n0 + wn * 64 + nf * 16 + fr;
#pragma unroll
            for (int r = 0; r < 4; r++) {
                int rowg = m0 + wm * 64 + mf * 16 + kb * 4 + r;
                if (rowg < M) {
                    float o = acc[mf][nf][r];
                    if (ADD) o += Src[(size_t)rowg * N + col];
                    C[(size_t)rowg * N + col] = o;
                }
            }
        }
}

// ---------------- softmax over batch dim (8 planes), fp32 in -> fp16 out ----------------
__global__ __launch_bounds__(256) void softmax_f16(
    const float* __restrict__ P, short* __restrict__ Q, int nElem, long ps)
{
    int i4 = (blockIdx.x * 256 + threadIdx.x) * 4;
    if (i4 >= nElem) return;
    float4 v[Bz];
    float4 mx = make_float4(-1e30f, -1e30f, -1e30f, -1e30f);
#pragma unroll
    for (int b = 0; b < Bz; b++) {
        v[b] = *(const float4*)(P + i4 + (size_t)b * ps);
        mx.x = fmaxf(mx.x, v[b].x); mx.y = fmaxf(mx.y, v[b].y);
        mx.z = fmaxf(mx.z, v[b].z); mx.w = fmaxf(mx.w, v[b].w);
    }
    float4 sum = make_float4(0.f, 0.f, 0.f, 0.f);
#pragma unroll
    for (int b = 0; b < Bz; b++) {
        v[b].x = __expf(v[b].x - mx.x); v[b].y = __expf(v[b].y - mx.y);
        v[b].z = __expf(v[b].z - mx.z); v[b].w = __expf(v[b].w - mx.w);
        sum.x += v[b].x; sum.y += v[b].y; sum.z += v[b].z; sum.w += v[b].w;
    }
    float4 inv = make_float4(1.f / sum.x, 1.f / sum.y, 1.f / sum.z, 1.f / sum.w);
#pragma unroll
    for (int b = 0; b < Bz; b++) {
        short4v r;
        r[0] = f2h(v[b].x * inv.x); r[1] = f2h(v[b].y * inv.y);
        r[2] = f2h(v[b].z * inv.z); r[3] = f2h(v[b].w * inv.w);
        *(short4v*)(Q + i4 + (size_t)b * ps) = r;
    }
}

// ---------------- moca 5x5 conv over fp16 {G_sm, A_sm} -> fp16 M ----------------
__global__ __launch_bounds__(256) void moca_kernel(
    const short* __restrict__ Gs, const short* __restrict__ As,
    const float* __restrict__ w3, const float* __restrict__ b3,
    short* __restrict__ Mout,
    int s0, int rlo, long psIn, long psOut)
{
    __shared__ float w[50];
    __shared__ float bb;
    int tid = threadIdx.x;
    if (tid < 50) w[tid] = w3[tid];
    if (tid == 50) bb = b3[0];
    __syncthreads();

    int t8 = tid * 8;
    int so = blockIdx.y, b = blockIdx.z;
    int s = s0 + so;
    const short* Gp = Gs + (size_t)b * psIn;
    const short* Ap = As + (size_t)b * psIn;

    float acc[8];
#pragma unroll
    for (int q = 0; q < 8; q++) acc[q] = bb;

#pragma unroll
    for (int i = 0; i < 5; i++) {
        int sr = s + i - 2;
        if (sr < 0 || sr >= Sz) continue;
        size_t ro = (size_t)(sr - rlo) * Sz;
        float gw[16], aw[16];
#pragma unroll
        for (int g = 0; g < 4; g++) {
            int c0 = t8 - 4 + g * 4;
            if (c0 >= 0 && c0 + 3 < Sz) {
                short4v gv = *(const short4v*)(Gp + ro + c0);
                short4v av = *(const short4v*)(Ap + ro + c0);
#pragma unroll
                for (int e = 0; e < 4; e++) { gw[g * 4 + e] = h2f(gv[e]); aw[g * 4 + e] = h2f(av[e]); }
            } else {
#pragma unroll
                for (int e = 0; e < 4; e++) { gw[g * 4 + e] = 0.f; aw[g * 4 + e] = 0.f; }
            }
        }
#pragma unroll
        for (int j = 0; j < 5; j++) {
            float wg = w[i * 5 + j], wa = w[25 + i * 5 + j];
#pragma unroll
            for (int q = 0; q < 8; q++)
                acc[q] = fmaf(wg, gw[q + j + 2], fmaf(wa, aw[q + j + 2], acc[q]));
        }
    }
    short4v r0, r1;
#pragma unroll
    for (int q = 0; q < 4; q++) { r0[q] = f2h(acc[q]); r1[q] = f2h(acc[q + 4]); }
    short* op = Mout + (size_t)b * psOut + (size_t)so * Sz + t8;
    *(short4v*)op = r0;
    *(short4v*)(op + 4) = r1;
}

// ---------------- host ----------------
extern "C" void kernel_launch(void* const* d_in, const int* in_sizes, int n_in,
                              void* d_out, int out_size, void* d_ws, size_t ws_size,
                              hipStream_t stream)
{
    const float* x  = (const float*)d_in[0];
    const float* w1 = (const float*)d_in[1];
    const float* b1 = (const float*)d_in[2];
    const float* w2 = (const float*)d_in[3];
    const float* b2 = (const float*)d_in[4];
    const float* w3 = (const float*)d_in[5];
    const float* b3 = (const float*)d_in[6];
    const float* w4 = (const float*)d_in[7];
    const float* b4 = (const float*)d_in[8];
    float* out = (float*)d_out;

    const size_t SD = (size_t)Sz * Dz;
    const size_t BSD2 = (size_t)Bz * SD * 2;     // 32MiB per fp16 [B,S,D] buffer

    char* ws = (char*)d_ws;
    short* x16 = (short*)(ws);
    short* C1f = (short*)(ws + 1 * BSD2);
    short* C2f = (short*)(ws + 2 * BSD2);
    short* C4T = (short*)(ws + 3 * BSD2);
    char* strip0 = ws + 4 * BSD2;                // 128MiB fixed

    // strip region: F fp32 logits (later aliased by M fp16) + Gsm + Asm fp16
    const int hs[5] = { 1024, 512, 256, 128, 64 };
    int h = 64;
    for (int i = 0; i < 5; i++) {
        size_t need = 4 * BSD2 + (size_t)131072 * (hs[i] + 4);  // Bz*PS*(4+2+2)
        if (need <= ws_size) { h = hs[i]; break; }
    }
    const size_t PS  = (size_t)(h + 4) * Sz;     // elems/plane for F/Gsm/Asm
    const size_t PSM = (size_t)h * Sz;           // elems/plane for M
    float* F   = (float*)strip0;
    short* Gsm = (short*)(F + (size_t)Bz * PS);
    short* Asm = Gsm + (size_t)Bz * PS;
    short* Mf  = (short*)strip0;                 // aliases F (dead after softmaxes)

    conv3_kernel<<<dim3(1, Sz, Bz), 256, 0, stream>>>(
        x, w1, b1, w2, b2, x16, C1f, C2f);
    convT_kernel<<<dim3(Sz / 64, Dz / 64, Bz), 256, 0, stream>>>(x, w4, b4, C4T);

    for (int s0 = 0; s0 < Sz; s0 += h) {
        int hcur = (Sz - s0 < h) ? (Sz - s0) : h;
        int rlo = s0 - 2; if (rlo < 0) rlo = 0;
        int rhi = s0 + hcur + 2; if (rhi > Sz) rhi = Sz;
        int nv = rhi - rlo;
        int ne = nv * Sz;
        dim3 g1(Sz / 128, (nv + 127) / 128, Bz);

        // G logits -> F -> softmax -> Gsm (fp16)
        gemm_f16<false><<<g1, 256, 0, stream>>>(
            x16 + (size_t)rlo * Dz, x16, nullptr, F,
            nv, Sz, Dz, (long)SD, (long)SD, (long)PS, 0);
        softmax_f16<<<(ne / 4 + 255) / 256, 256, 0, stream>>>(F, Gsm, ne, (long)PS);

        // A logits -> F (reuse) -> softmax -> Asm (fp16)
        gemm_f16<false><<<g1, 256, 0, stream>>>(
            C1f + (size_t)rlo * Dz, C2f, nullptr, F,
            nv, Sz, Dz, (long)SD, (long)SD, (long)PS, 0);
        softmax_f16<<<(ne / 4 + 255) / 256, 256, 0, stream>>>(F, Asm, ne, (long)PS);

        // moca -> Mf (aliases F)
        moca_kernel<<<dim3(1, hcur, Bz), 256, 0, stream>>>(
            Gsm, Asm, w3, b3, Mf, s0, rlo, (long)PS, (long)PSM);

        // Wz = M @ C4T^T + x -> out
        dim3 g2(Dz / 128, (hcur + 127) / 128, Bz);
        gemm_f16<true><<<g2, 256, 0, stream>>>(
            Mf, C4T, x + (size_t)s0 * Dz, out + (size_t)s0 * Dz,
            hcur, Dz, Sz, (long)PSM, (long)SD, (long)SD, (long)SD);
    }
}

// Round 6
// 809.904 us; speedup vs baseline: 2.6525x; 1.1472x over previous
//
// MoCA fused pipeline — round 6: 8-wave 128x128 fp16 MFMA GEMMs (512 thr),
// aligned strips {0,508,1016,1524} (kills 24% M-pad waste), LDS-free conv3,
// fused pair softmax. Fixed 128MiB + 104MB strip region.
#include <hip/hip_runtime.h>

#define Bz 8
#define Sz 2048
#define Dz 1024

typedef __attribute__((ext_vector_type(8))) _Float16 f16x8;
typedef __attribute__((ext_vector_type(4))) short short4v;
typedef __attribute__((ext_vector_type(4))) float f32x4;

__device__ __forceinline__ short f2h(float f) {
    _Float16 h = (_Float16)f;
    return __builtin_bit_cast(short, h);
}
__device__ __forceinline__ float h2f(short s) {
    return (float)__builtin_bit_cast(_Float16, s);
}
__device__ __forceinline__ void gld16(const void* g, void* l) {
    __builtin_amdgcn_global_load_lds(
        (const __attribute__((address_space(1))) void*)g,
        (__attribute__((address_space(3))) void*)l, 16, 0, 0);
}

// ---------------- fused 5x5 convs over x — LDS-free, direct global ----------------
// emits fp16: x16[s,d], C1f[s,d]=conv(w1)+b1, C2f[s,d]=conv(w2^T)+b2
__global__ __launch_bounds__(256) void conv3_kernel(
    const float* __restrict__ x,
    const float* __restrict__ w1, const float* __restrict__ b1,
    const float* __restrict__ w2, const float* __restrict__ b2,
    short* __restrict__ x16, short* __restrict__ C1f, short* __restrict__ C2f)
{
    __shared__ float w[50];
    __shared__ float bias[2];
    const size_t SD = (size_t)Sz * Dz;
    int tid = threadIdx.x;
    if (tid < 25) w[tid] = w1[tid];
    else if (tid < 50) w[tid] = w2[tid - 25];
    if (tid == 50) { bias[0] = b1[0]; bias[1] = b2[0]; }
    __syncthreads();

    int d4 = tid * 4;
    int s = blockIdx.y, b = blockIdx.z;
    const float* xb = x + (size_t)b * SD + d4;

    float o1[4] = {}, o2[4] = {}, xv[4];
#pragma unroll
    for (int i = 0; i < 5; i++) {
        int ss = s + i - 2;
        if (ss < 0 || ss >= Sz) continue;          // i==2 (ss==s) always valid
        const float* rp = xb + (size_t)ss * Dz;
        float wv[12];
        if (d4 > 0) *(float4*)&wv[0] = *(const float4*)(rp - 4);
        else { wv[0] = wv[1] = wv[2] = wv[3] = 0.f; }
        *(float4*)&wv[4] = *(const float4*)rp;
        if (d4 < 1020) *(float4*)&wv[8] = *(const float4*)(rp + 4);
        else { wv[8] = wv[9] = wv[10] = wv[11] = 0.f; }
        if (i == 2) { xv[0] = wv[4]; xv[1] = wv[5]; xv[2] = wv[6]; xv[3] = wv[7]; }
#pragma unroll
        for (int j = 0; j < 5; j++) {
            float c1w = w[i * 5 + j], c2w = w[25 + j * 5 + i];
#pragma unroll
            for (int q = 0; q < 4; q++) {
                float v = wv[q + j + 2];
                o1[q] = fmaf(c1w, v, o1[q]);
                o2[q] = fmaf(c2w, v, o2[q]);
            }
        }
    }
    size_t o = (size_t)b * SD + (size_t)s * Dz + d4;
    short4v hx, h1, h2;
#pragma unroll
    for (int q = 0; q < 4; q++) {
        hx[q] = f2h(xv[q]);
        h1[q] = f2h(o1[q] + bias[0]);
        h2[q] = f2h(o2[q] + bias[1]);
    }
    *(short4v*)(x16 + o) = hx;
    *(short4v*)(C1f + o) = h1;
    *(short4v*)(C2f + o) = h2;
}

// ---------------- fused conv_g (5x5) + transpose: x[s,d] -> C4T[d,s] fp16 ----------------
__global__ __launch_bounds__(256) void convT_kernel(
    const float* __restrict__ x, const float* __restrict__ w4,
    const float* __restrict__ b4, short* __restrict__ C4T)
{
    __shared__ float xs[68][73];
    __shared__ short ct[64][72];
    __shared__ float w[25];
    __shared__ float bb;
    const size_t SD = (size_t)Sz * Dz;
    int tid = threadIdx.x;
    if (tid < 25) w[tid] = w4[tid];
    if (tid == 25) bb = b4[0];

    int s0 = blockIdx.x * 64, d0 = blockIdx.y * 64, b = blockIdx.z;
    const float* xb = x + (size_t)b * SD;
    for (int k = tid; k < 68 * 68; k += 256) {
        int r = k / 68, c = k - r * 68;
        int gr = s0 - 2 + r, gc = d0 - 2 + c;
        float v = 0.f;
        if (gr >= 0 && gr < Sz && gc >= 0 && gc < Dz) v = xb[(size_t)gr * Dz + gc];
        xs[r][c] = v;
    }
    __syncthreads();

    int sl = tid & 63, dg = tid >> 6;
    float acc[16];
#pragma unroll
    for (int q = 0; q < 16; q++) acc[q] = bb;
#pragma unroll
    for (int i = 0; i < 5; i++) {
        float row[20];
#pragma unroll
        for (int m = 0; m < 20; m++) row[m] = xs[sl + i][dg * 16 + m];
#pragma unroll
        for (int j = 0; j < 5; j++) {
            float wv = w[i * 5 + j];
#pragma unroll
            for (int q = 0; q < 16; q++) acc[q] = fmaf(wv, row[q + j], acc[q]);
        }
    }
#pragma unroll
    for (int q = 0; q < 16; q++) ct[dg * 16 + q][sl] = f2h(acc[q]);
    __syncthreads();

    int dl = tid >> 2, sc = (tid & 3) * 16;
    f16x8 v0 = *(const f16x8*)&ct[dl][sc];
    f16x8 v1 = *(const f16x8*)&ct[dl][sc + 8];
    short* op = C4T + (size_t)b * SD + (size_t)(d0 + dl) * Sz + s0 + sc;
    *(f16x8*)op = v0;
    *(f16x8*)(op + 8) = v1;
}

// ---------------- fp16 MFMA NT GEMM, 128x128 tile, 8 waves (512 thr) ----------------
// C[m,n] = A[m,:]·B[n,:] (+Src[m,n] if ADD), fp32 out. BK=64,
// global_load_lds w=16 + both-sides XOR swizzle. Waves 2Mx4N, 64x32 each.
template <bool ADD>
__global__ __launch_bounds__(512) void gemm_f16(
    const short* __restrict__ A, const short* __restrict__ B,
    const float* __restrict__ Src, float* __restrict__ C,
    int M, int N, int K,
    long sAb, long sBb, long sCb, long sSb)
{
    __shared__ short ldsA[128 * 64];
    __shared__ short ldsB[128 * 64];

    const int bz = blockIdx.z;
    A += (size_t)bz * sAb; B += (size_t)bz * sBb;
    C += (size_t)bz * sCb;
    if (ADD) Src += (size_t)bz * sSb;

    const int m0 = blockIdx.y * 128, n0 = blockIdx.x * 128;
    const int t = threadIdx.x;
    const int lane = t & 63;
    const int w = t >> 6;                 // 0..7
    const int wm = w >> 2, wn = w & 3;    // 2 x 4 wave grid; wave tile 64x32
    const int fr = lane & 15;
    const int kb = lane >> 4;
    const int swz = (fr & 7) << 4;        // read-side XOR: (row&7)<<4 bytes

    const int sr_ = t >> 3;               // staging row within 64-row chunk
    const int scb = (t & 7) * 16;         // staging col byte

    f32x4 acc[4][2];
#pragma unroll
    for (int i = 0; i < 4; i++)
#pragma unroll
        for (int j = 0; j < 2; j++) acc[i][j] = (f32x4){0.f, 0.f, 0.f, 0.f};

    for (int k0 = 0; k0 < K; k0 += 64) {
        __syncthreads();                  // previous tile fully consumed
#pragma unroll
        for (int c = 0; c < 2; c++) {
            int r = c * 64 + sr_;
            int row = m0 + r; if (row > M - 1) row = M - 1;
            int cb = scb ^ ((r & 7) << 4);    // inverse-swizzled SOURCE col
            gld16((const char*)A + ((size_t)row * K + k0) * 2 + cb,
                  (char*)ldsA + c * 8192 + t * 16);
        }
#pragma unroll
        for (int c = 0; c < 2; c++) {
            int r = c * 64 + sr_;
            int cb = scb ^ ((r & 7) << 4);
            gld16((const char*)B + ((size_t)(n0 + r) * K + k0) * 2 + cb,
                  (char*)ldsB + c * 8192 + t * 16);
        }
        __syncthreads();                  // drain + barrier: tile ready
#pragma unroll
        for (int ks = 0; ks < 2; ks++) {
            f16x8 af[4], bfr[2];
#pragma unroll
            for (int f = 0; f < 4; f++) {
                int rowA = wm * 64 + f * 16 + fr;
                af[f] = *(const f16x8*)((const char*)ldsA + rowA * 128 + ((ks * 64 + kb * 16) ^ swz));
            }
#pragma unroll
            for (int g = 0; g < 2; g++) {
                int rowB = wn * 32 + g * 16 + fr;
                bfr[g] = *(const f16x8*)((const char*)ldsB + rowB * 128 + ((ks * 64 + kb * 16) ^ swz));
            }
#pragma unroll
            for (int mf = 0; mf < 4; mf++)
#pragma unroll
                for (int nf = 0; nf < 2; nf++)
                    acc[mf][nf] = __builtin_amdgcn_mfma_f32_16x16x32_f16(af[mf], bfr[nf], acc[mf][nf], 0, 0, 0);
        }
    }

#pragma unroll
    for (int mf = 0; mf < 4; mf++)
#pragma unroll
        for (int nf = 0; nf < 2; nf++) {
            int col = n0 + wn * 32 + nf * 16 + fr;
#pragma unroll
            for (int r = 0; r < 4; r++) {
                int rowg = m0 + wm * 64 + mf * 16 + kb * 4 + r;
                if (rowg < M) {
                    float o = acc[mf][nf][r];
                    if (ADD) o += Src[(size_t)rowg * N + col];
                    C[(size_t)rowg * N + col] = o;
                }
            }
        }
}

// ---------------- pair softmax over batch dim, fp32 in -> fp16 out ----------------
__global__ __launch_bounds__(256) void softmax2_f16(
    const float* __restrict__ Pg, const float* __restrict__ Pa,
    short* __restrict__ Qg, short* __restrict__ Qa, int nElem, long ps)
{
    int i4 = (blockIdx.x * 256 + threadIdx.x) * 4;
    if (i4 >= nElem) return;
#pragma unroll
    for (int m = 0; m < 2; m++) {
        const float* P = m ? Pa : Pg;
        short* Q = m ? Qa : Qg;
        float4 v[Bz];
        float4 mx = make_float4(-1e30f, -1e30f, -1e30f, -1e30f);
#pragma unroll
        for (int b = 0; b < Bz; b++) {
            v[b] = *(const float4*)(P + i4 + (size_t)b * ps);
            mx.x = fmaxf(mx.x, v[b].x); mx.y = fmaxf(mx.y, v[b].y);
            mx.z = fmaxf(mx.z, v[b].z); mx.w = fmaxf(mx.w, v[b].w);
        }
        float4 sum = make_float4(0.f, 0.f, 0.f, 0.f);
#pragma unroll
        for (int b = 0; b < Bz; b++) {
            v[b].x = __expf(v[b].x - mx.x); v[b].y = __expf(v[b].y - mx.y);
            v[b].z = __expf(v[b].z - mx.z); v[b].w = __expf(v[b].w - mx.w);
            sum.x += v[b].x; sum.y += v[b].y; sum.z += v[b].z; sum.w += v[b].w;
        }
        float4 inv = make_float4(1.f / sum.x, 1.f / sum.y, 1.f / sum.z, 1.f / sum.w);
#pragma unroll
        for (int b = 0; b < Bz; b++) {
            short4v r;
            r[0] = f2h(v[b].x * inv.x); r[1] = f2h(v[b].y * inv.y);
            r[2] = f2h(v[b].z * inv.z); r[3] = f2h(v[b].w * inv.w);
            *(short4v*)(Q + i4 + (size_t)b * ps) = r;
        }
    }
}

// ---------------- moca 5x5 conv over fp16 {G_sm, A_sm} -> fp16 M ----------------
__global__ __launch_bounds__(256) void moca_kernel(
    const short* __restrict__ Gs, const short* __restrict__ As,
    const float* __restrict__ w3, const float* __restrict__ b3,
    short* __restrict__ Mout,
    int o0, int rlo, long psIn, long psOut)
{
    __shared__ float w[50];
    __shared__ float bb;
    int tid = threadIdx.x;
    if (tid < 50) w[tid] = w3[tid];
    if (tid == 50) bb = b3[0];
    __syncthreads();

    int t8 = tid * 8;
    int so = blockIdx.y, b = blockIdx.z;
    int s = o0 + so;
    const short* Gp = Gs + (size_t)b * psIn;
    const short* Ap = As + (size_t)b * psIn;

    float acc[8];
#pragma unroll
    for (int q = 0; q < 8; q++) acc[q] = bb;

#pragma unroll
    for (int i = 0; i < 5; i++) {
        int sr = s + i - 2;
        if (sr < 0 || sr >= Sz) continue;
        size_t ro = (size_t)(sr - rlo) * Sz;
        float gw[16], aw[16];
#pragma unroll
        for (int g = 0; g < 4; g++) {
            int c0 = t8 - 4 + g * 4;
            if (c0 >= 0 && c0 + 3 < Sz) {
                short4v gv = *(const short4v*)(Gp + ro + c0);
                short4v av = *(const short4v*)(Ap + ro + c0);
#pragma unroll
                for (int e = 0; e < 4; e++) { gw[g * 4 + e] = h2f(gv[e]); aw[g * 4 + e] = h2f(av[e]); }
            } else {
#pragma unroll
                for (int e = 0; e < 4; e++) { gw[g * 4 + e] = 0.f; aw[g * 4 + e] = 0.f; }
            }
        }
#pragma unroll
        for (int j = 0; j < 5; j++) {
            float wg = w[i * 5 + j], wa = w[25 + i * 5 + j];
#pragma unroll
            for (int q = 0; q < 8; q++)
                acc[q] = fmaf(wg, gw[q + j + 2], fmaf(wa, aw[q + j + 2], acc[q]));
        }
    }
    short4v r0, r1;
#pragma unroll
    for (int q = 0; q < 4; q++) { r0[q] = f2h(acc[q]); r1[q] = f2h(acc[q + 4]); }
    short* op = Mout + (size_t)b * psOut + (size_t)so * Sz + t8;
    *(short4v*)op = r0;
    *(short4v*)(op + 4) = r1;
}

// ---------------- host ----------------
extern "C" void kernel_launch(void* const* d_in, const int* in_sizes, int n_in,
                              void* d_out, int out_size, void* d_ws, size_t ws_size,
                              hipStream_t stream)
{
    const float* x  = (const float*)d_in[0];
    const float* w1 = (const float*)d_in[1];
    const float* b1 = (const float*)d_in[2];
    const float* w2 = (const float*)d_in[3];
    const float* b2 = (const float*)d_in[4];
    const float* w3 = (const float*)d_in[5];
    const float* b3 = (const float*)d_in[6];
    const float* w4 = (const float*)d_in[7];
    const float* b4 = (const float*)d_in[8];
    float* out = (float*)d_out;

    const size_t SD = (size_t)Sz * Dz;
    const size_t BSD2 = (size_t)Bz * SD * 2;     // 32MiB per fp16 [B,S,D] buffer

    char* ws = (char*)d_ws;
    short* x16 = (short*)(ws);
    short* C1f = (short*)(ws + 1 * BSD2);
    short* C2f = (short*)(ws + 2 * BSD2);
    short* C4T = (short*)(ws + 3 * BSD2);
    char* strip0 = ws + 4 * BSD2;                // 128MiB fixed

    // strip region (PS = 528 rows): F_G, F_A fp32 + Gsm, Asm fp16 = 103.8MB
    const size_t PS = (size_t)528 * Sz;
    float* Fg  = (float*)strip0;
    float* Fa  = Fg + (size_t)Bz * PS;
    short* Gsm = (short*)(Fa + (size_t)Bz * PS);
    short* Asm = Gsm + (size_t)Bz * PS;
    short* Mf  = (short*)strip0;                 // aliases Fg (dead after softmax)

    conv3_kernel<<<dim3(1, Sz, Bz), 256, 0, stream>>>(
        x, w1, b1, w2, b2, x16, C1f, C2f);
    convT_kernel<<<dim3(Sz / 64, Dz / 64, Bz), 256, 0, stream>>>(x, w4, b4, C4T);

    const int o0s[5] = { 0, 508, 1016, 1524, 2048 };
    for (int k = 0; k < 4; k++) {
        int o0 = o0s[k], o1 = o0s[k + 1];
        int hcur = o1 - o0;
        int rlo = o0 - 2; if (rlo < 0) rlo = 0;
        int rhi = o1 + 2; if (rhi > Sz) rhi = Sz;
        int nv = rhi - rlo;                       // 510, 512, 512, 526
        int ne = nv * Sz;
        dim3 g1(Sz / 128, (nv + 127) / 128, Bz);

        // logit GEMMs -> Fg, Fa
        gemm_f16<false><<<g1, 512, 0, stream>>>(
            x16 + (size_t)rlo * Dz, x16, nullptr, Fg,
            nv, Sz, Dz, (long)SD, (long)SD, (long)PS, 0);
        gemm_f16<false><<<g1, 512, 0, stream>>>(
            C1f + (size_t)rlo * Dz, C2f, nullptr, Fa,
            nv, Sz, Dz, (long)SD, (long)SD, (long)PS, 0);

        // pair softmax -> Gsm, Asm (fp16)
        softmax2_f16<<<(ne / 4 + 255) / 256, 256, 0, stream>>>(
            Fg, Fa, Gsm, Asm, ne, (long)PS);

        // moca -> Mf (aliases Fg)
        moca_kernel<<<dim3(1, hcur, Bz), 256, 0, stream>>>(
            Gsm, Asm, w3, b3, Mf, o0, rlo, (long)PS, (long)((size_t)hcur * Sz));

        // Wz = M @ C4T^T + x -> out
        dim3 g2(Dz / 128, (hcur + 127) / 128, Bz);
        gemm_f16<true><<<g2, 512, 0, stream>>>(
            Mf, C4T, x + (size_t)o0 * Dz, out + (size_t)o0 * Dz,
            hcur, Dz, Sz, (long)((size_t)hcur * Sz), (long)SD, (long)SD, (long)SD);
    }
}

// Round 7
// 772.589 us; speedup vs baseline: 2.7806x; 1.0483x over previous
//
// MoCA fused pipeline — round 7: dbuf 2-phase prefetch GEMMs (T3-min recipe),
// fused dual-map logit dispatch (z=16), XCD-chunked conv3 (kills 2.4x re-fetch).
#include <hip/hip_runtime.h>

#define Bz 8
#define Sz 2048
#define Dz 1024

typedef __attribute__((ext_vector_type(8))) _Float16 f16x8;
typedef __attribute__((ext_vector_type(4))) short short4v;
typedef __attribute__((ext_vector_type(4))) float f32x4;

__device__ __forceinline__ short f2h(float f) {
    _Float16 h = (_Float16)f;
    return __builtin_bit_cast(short, h);
}
__device__ __forceinline__ float h2f(short s) {
    return (float)__builtin_bit_cast(_Float16, s);
}
__device__ __forceinline__ void gld16(const void* g, void* l) {
    __builtin_amdgcn_global_load_lds(
        (const __attribute__((address_space(1))) void*)g,
        (__attribute__((address_space(3))) void*)l, 16, 0, 0);
}

// ---------------- fused 5x5 convs over x — LDS-free, XCD-chunked rows ----------------
// s = (y&7)*256 + (y>>3): each XCD owns a contiguous 256-row band -> L2 reuse of halos.
__global__ __launch_bounds__(256) void conv3_kernel(
    const float* __restrict__ x,
    const float* __restrict__ w1, const float* __restrict__ b1,
    const float* __restrict__ w2, const float* __restrict__ b2,
    short* __restrict__ x16, short* __restrict__ C1f, short* __restrict__ C2f)
{
    __shared__ float w[50];
    __shared__ float bias[2];
    const size_t SD = (size_t)Sz * Dz;
    int tid = threadIdx.x;
    if (tid < 25) w[tid] = w1[tid];
    else if (tid < 50) w[tid] = w2[tid - 25];
    if (tid == 50) { bias[0] = b1[0]; bias[1] = b2[0]; }
    __syncthreads();

    int d4 = tid * 4;
    int y = blockIdx.y;
    int s = ((y & 7) << 8) | (y >> 3);         // XCD-chunked row mapping
    int b = blockIdx.z;
    const float* xb = x + (size_t)b * SD + d4;

    float o1[4] = {}, o2[4] = {}, xv[4];
#pragma unroll
    for (int i = 0; i < 5; i++) {
        int ss = s + i - 2;
        if (ss < 0 || ss >= Sz) continue;
        const float* rp = xb + (size_t)ss * Dz;
        float wv[12];
        if (d4 > 0) *(float4*)&wv[0] = *(const float4*)(rp - 4);
        else { wv[0] = wv[1] = wv[2] = wv[3] = 0.f; }
        *(float4*)&wv[4] = *(const float4*)rp;
        if (d4 < 1020) *(float4*)&wv[8] = *(const float4*)(rp + 4);
        else { wv[8] = wv[9] = wv[10] = wv[11] = 0.f; }
        if (i == 2) { xv[0] = wv[4]; xv[1] = wv[5]; xv[2] = wv[6]; xv[3] = wv[7]; }
#pragma unroll
        for (int j = 0; j < 5; j++) {
            float c1w = w[i * 5 + j], c2w = w[25 + j * 5 + i];
#pragma unroll
            for (int q = 0; q < 4; q++) {
                float v = wv[q + j + 2];
                o1[q] = fmaf(c1w, v, o1[q]);
                o2[q] = fmaf(c2w, v, o2[q]);
            }
        }
    }
    size_t o = (size_t)b * SD + (size_t)s * Dz + d4;
    short4v hx, h1, h2;
#pragma unroll
    for (int q = 0; q < 4; q++) {
        hx[q] = f2h(xv[q]);
        h1[q] = f2h(o1[q] + bias[0]);
        h2[q] = f2h(o2[q] + bias[1]);
    }
    *(short4v*)(x16 + o) = hx;
    *(short4v*)(C1f + o) = h1;
    *(short4v*)(C2f + o) = h2;
}

// ---------------- fused conv_g (5x5) + transpose: x[s,d] -> C4T[d,s] fp16 ----------------
__global__ __launch_bounds__(256) void convT_kernel(
    const float* __restrict__ x, const float* __restrict__ w4,
    const float* __restrict__ b4, short* __restrict__ C4T)
{
    __shared__ float xs[68][73];
    __shared__ short ct[64][72];
    __shared__ float w[25];
    __shared__ float bb;
    const size_t SD = (size_t)Sz * Dz;
    int tid = threadIdx.x;
    if (tid < 25) w[tid] = w4[tid];
    if (tid == 25) bb = b4[0];

    int s0 = blockIdx.x * 64, d0 = blockIdx.y * 64, b = blockIdx.z;
    const float* xb = x + (size_t)b * SD;
    for (int k = tid; k < 68 * 68; k += 256) {
        int r = k / 68, c = k - r * 68;
        int gr = s0 - 2 + r, gc = d0 - 2 + c;
        float v = 0.f;
        if (gr >= 0 && gr < Sz && gc >= 0 && gc < Dz) v = xb[(size_t)gr * Dz + gc];
        xs[r][c] = v;
    }
    __syncthreads();

    int sl = tid & 63, dg = tid >> 6;
    float acc[16];
#pragma unroll
    for (int q = 0; q < 16; q++) acc[q] = bb;
#pragma unroll
    for (int i = 0; i < 5; i++) {
        float row[20];
#pragma unroll
        for (int m = 0; m < 20; m++) row[m] = xs[sl + i][dg * 16 + m];
#pragma unroll
        for (int j = 0; j < 5; j++) {
            float wv = w[i * 5 + j];
#pragma unroll
            for (int q = 0; q < 16; q++) acc[q] = fmaf(wv, row[q + j], acc[q]);
        }
    }
#pragma unroll
    for (int q = 0; q < 16; q++) ct[dg * 16 + q][sl] = f2h(acc[q]);
    __syncthreads();

    int dl = tid >> 2, sc = (tid & 3) * 16;
    f16x8 v0 = *(const f16x8*)&ct[dl][sc];
    f16x8 v1 = *(const f16x8*)&ct[dl][sc + 8];
    short* op = C4T + (size_t)b * SD + (size_t)(d0 + dl) * Sz + s0 + sc;
    *(f16x8*)op = v0;
    *(f16x8*)(op + 8) = v1;
}

// ---------------- fp16 MFMA NT GEMM — dbuf 2-phase prefetch, dual-map ----------------
// map = blockIdx.z>>3 selects (A0,B0,C0) vs (A1,B1,C1); batch = blockIdx.z&7.
// 128x128 tile, BK=64, 8 waves (2Mx4N, 64x32 each), global_load_lds + XOR swizzle.
// Pipeline: STAGE(buf0); bar; { STAGE(nxt); COMPUTE(cur); bar; } ...; COMPUTE(last).
template <bool ADD>
__global__ __launch_bounds__(512) void gemm_f16(
    const short* __restrict__ A0, const short* __restrict__ B0,
    const short* __restrict__ A1, const short* __restrict__ B1,
    const float* __restrict__ Src, float* __restrict__ C0, float* __restrict__ C1g,
    int M, int N, int K,
    long sAb, long sBb, long sCb, long sSb)
{
    __shared__ short sA[2][128 * 64];
    __shared__ short sB[2][128 * 64];

    const int zz = blockIdx.z;
    const int map = zz >> 3, bz = zz & 7;
    const short* A = (map ? A1 : A0) + (size_t)bz * sAb;
    const short* B = (map ? B1 : B0) + (size_t)bz * sBb;
    float* C = (map ? C1g : C0) + (size_t)bz * sCb;
    if (ADD) Src += (size_t)bz * sSb;

    const int m0 = blockIdx.y * 128, n0 = blockIdx.x * 128;
    const int t = threadIdx.x;
    const int lane = t & 63;
    const int w = t >> 6;
    const int wm = w >> 2, wn = w & 3;     // 2x4 wave grid; wave tile 64x32
    const int fr = lane & 15;
    const int kb = lane >> 4;
    const int swz = (fr & 7) << 4;

    const int sr_ = t >> 3;                // 0..63
    const int scb = (t & 7) * 16;

    f32x4 acc[4][2];
#pragma unroll
    for (int i = 0; i < 4; i++)
#pragma unroll
        for (int j = 0; j < 2; j++) acc[i][j] = (f32x4){0.f, 0.f, 0.f, 0.f};

    auto STAGE = [&](int buf, int k0) {
#pragma unroll
        for (int c = 0; c < 2; c++) {
            int r = c * 64 + sr_;
            int rowA = m0 + r; if (rowA > M - 1) rowA = M - 1;
            int cb = scb ^ ((r & 7) << 4);
            gld16((const char*)A + ((size_t)rowA * K + k0) * 2 + cb,
                  (char*)&sA[buf][0] + c * 8192 + t * 16);
            gld16((const char*)B + ((size_t)(n0 + r) * K + k0) * 2 + cb,
                  (char*)&sB[buf][0] + c * 8192 + t * 16);
        }
    };
    auto COMPUTE = [&](int buf) {
#pragma unroll
        for (int ks = 0; ks < 2; ks++) {
            f16x8 af[4], bfr[2];
#pragma unroll
            for (int f = 0; f < 4; f++) {
                int rowA = wm * 64 + f * 16 + fr;
                af[f] = *(const f16x8*)((const char*)&sA[buf][0] + rowA * 128 + ((ks * 64 + kb * 16) ^ swz));
            }
#pragma unroll
            for (int g = 0; g < 2; g++) {
                int rowB = wn * 32 + g * 16 + fr;
                bfr[g] = *(const f16x8*)((const char*)&sB[buf][0] + rowB * 128 + ((ks * 64 + kb * 16) ^ swz));
            }
#pragma unroll
            for (int mf = 0; mf < 4; mf++)
#pragma unroll
                for (int nf = 0; nf < 2; nf++)
                    acc[mf][nf] = __builtin_amdgcn_mfma_f32_16x16x32_f16(af[mf], bfr[nf], acc[mf][nf], 0, 0, 0);
        }
    };

    STAGE(0, 0);
    __syncthreads();                       // vmcnt(0) drain: buf0 ready
    int cur = 0;
    const int nIter = K / 64;
    for (int it = 1; it < nIter; it++) {
        STAGE(cur ^ 1, it * 64);           // issue next-tile loads (in flight)
        COMPUTE(cur);                      // ds_read + MFMA current tile
        __syncthreads();                   // drain + barrier: next tile ready
        cur ^= 1;
    }
    COMPUTE(cur);

#pragma unroll
    for (int mf = 0; mf < 4; mf++)
#pragma unroll
        for (int nf = 0; nf < 2; nf++) {
            int col = n0 + wn * 32 + nf * 16 + fr;
#pragma unroll
            for (int r = 0; r < 4; r++) {
                int rowg = m0 + wm * 64 + mf * 16 + kb * 4 + r;
                if (rowg < M) {
                    float o = acc[mf][nf][r];
                    if (ADD) o += Src[(size_t)rowg * N + col];
                    C[(size_t)rowg * N + col] = o;
                }
            }
        }
}

// ---------------- pair softmax over batch dim, fp32 in -> fp16 out ----------------
__global__ __launch_bounds__(256) void softmax2_f16(
    const float* __restrict__ Pg, const float* __restrict__ Pa,
    short* __restrict__ Qg, short* __restrict__ Qa, int nElem, long ps)
{
    int i4 = (blockIdx.x * 256 + threadIdx.x) * 4;
    if (i4 >= nElem) return;
#pragma unroll
    for (int m = 0; m < 2; m++) {
        const float* P = m ? Pa : Pg;
        short* Q = m ? Qa : Qg;
        float4 v[Bz];
        float4 mx = make_float4(-1e30f, -1e30f, -1e30f, -1e30f);
#pragma unroll
        for (int b = 0; b < Bz; b++) {
            v[b] = *(const float4*)(P + i4 + (size_t)b * ps);
            mx.x = fmaxf(mx.x, v[b].x); mx.y = fmaxf(mx.y, v[b].y);
            mx.z = fmaxf(mx.z, v[b].z); mx.w = fmaxf(mx.w, v[b].w);
        }
        float4 sum = make_float4(0.f, 0.f, 0.f, 0.f);
#pragma unroll
        for (int b = 0; b < Bz; b++) {
            v[b].x = __expf(v[b].x - mx.x); v[b].y = __expf(v[b].y - mx.y);
            v[b].z = __expf(v[b].z - mx.z); v[b].w = __expf(v[b].w - mx.w);
            sum.x += v[b].x; sum.y += v[b].y; sum.z += v[b].z; sum.w += v[b].w;
        }
        float4 inv = make_float4(1.f / sum.x, 1.f / sum.y, 1.f / sum.z, 1.f / sum.w);
#pragma unroll
        for (int b = 0; b < Bz; b++) {
            short4v r;
            r[0] = f2h(v[b].x * inv.x); r[1] = f2h(v[b].y * inv.y);
            r[2] = f2h(v[b].z * inv.z); r[3] = f2h(v[b].w * inv.w);
            *(short4v*)(Q + i4 + (size_t)b * ps) = r;
        }
    }
}

// ---------------- moca 5x5 conv over fp16 {G_sm, A_sm} -> fp16 M ----------------
__global__ __launch_bounds__(256) void moca_kernel(
    const short* __restrict__ Gs, const short* __restrict__ As,
    const float* __restrict__ w3, const float* __restrict__ b3,
    short* __restrict__ Mout,
    int o0, int rlo, long psIn, long psOut)
{
    __shared__ float w[50];
    __shared__ float bb;
    int tid = threadIdx.x;
    if (tid < 50) w[tid] = w3[tid];
    if (tid == 50) bb = b3[0];
    __syncthreads();

    int t8 = tid * 8;
    int so = blockIdx.y, b = blockIdx.z;
    int s = o0 + so;
    const short* Gp = Gs + (size_t)b * psIn;
    const short* Ap = As + (size_t)b * psIn;

    float acc[8];
#pragma unroll
    for (int q = 0; q < 8; q++) acc[q] = bb;

#pragma unroll
    for (int i = 0; i < 5; i++) {
        int sr = s + i - 2;
        if (sr < 0 || sr >= Sz) continue;
        size_t ro = (size_t)(sr - rlo) * Sz;
        float gw[16], aw[16];
#pragma unroll
        for (int g = 0; g < 4; g++) {
            int c0 = t8 - 4 + g * 4;
            if (c0 >= 0 && c0 + 3 < Sz) {
                short4v gv = *(const short4v*)(Gp + ro + c0);
                short4v av = *(const short4v*)(Ap + ro + c0);
#pragma unroll
                for (int e = 0; e < 4; e++) { gw[g * 4 + e] = h2f(gv[e]); aw[g * 4 + e] = h2f(av[e]); }
            } else {
#pragma unroll
                for (int e = 0; e < 4; e++) { gw[g * 4 + e] = 0.f; aw[g * 4 + e] = 0.f; }
            }
        }
#pragma unroll
        for (int j = 0; j < 5; j++) {
            float wg = w[i * 5 + j], wa = w[25 + i * 5 + j];
#pragma unroll
            for (int q = 0; q < 8; q++)
                acc[q] = fmaf(wg, gw[q + j + 2], fmaf(wa, aw[q + j + 2], acc[q]));
        }
    }
    short4v r0, r1;
#pragma unroll
    for (int q = 0; q < 4; q++) { r0[q] = f2h(acc[q]); r1[q] = f2h(acc[q + 4]); }
    short* op = Mout + (size_t)b * psOut + (size_t)so * Sz + t8;
    *(short4v*)op = r0;
    *(short4v*)(op + 4) = r1;
}

// ---------------- host ----------------
extern "C" void kernel_launch(void* const* d_in, const int* in_sizes, int n_in,
                              void* d_out, int out_size, void* d_ws, size_t ws_size,
                              hipStream_t stream)
{
    const float* x  = (const float*)d_in[0];
    const float* w1 = (const float*)d_in[1];
    const float* b1 = (const float*)d_in[2];
    const float* w2 = (const float*)d_in[3];
    const float* b2 = (const float*)d_in[4];
    const float* w3 = (const float*)d_in[5];
    const float* b3 = (const float*)d_in[6];
    const float* w4 = (const float*)d_in[7];
    const float* b4 = (const float*)d_in[8];
    float* out = (float*)d_out;

    const size_t SD = (size_t)Sz * Dz;
    const size_t BSD2 = (size_t)Bz * SD * 2;     // 32MiB per fp16 [B,S,D] buffer

    char* ws = (char*)d_ws;
    short* x16 = (short*)(ws);
    short* C1f = (short*)(ws + 1 * BSD2);
    short* C2f = (short*)(ws + 2 * BSD2);
    short* C4T = (short*)(ws + 3 * BSD2);
    char* strip0 = ws + 4 * BSD2;                // 128MiB fixed

    // strip region (PS = 528 rows): F_G, F_A fp32 + Gsm, Asm fp16 = 103.8MB
    const size_t PS = (size_t)528 * Sz;
    float* Fg  = (float*)strip0;
    float* Fa  = Fg + (size_t)Bz * PS;
    short* Gsm = (short*)(Fa + (size_t)Bz * PS);
    short* Asm = Gsm + (size_t)Bz * PS;
    short* Mf  = (short*)strip0;                 // aliases Fg (dead after softmax)

    conv3_kernel<<<dim3(1, Sz, Bz), 256, 0, stream>>>(
        x, w1, b1, w2, b2, x16, C1f, C2f);
    convT_kernel<<<dim3(Sz / 64, Dz / 64, Bz), 256, 0, stream>>>(x, w4, b4, C4T);

    const int o0s[5] = { 0, 508, 1016, 1524, 2048 };
    for (int k = 0; k < 4; k++) {
        int o0 = o0s[k], o1 = o0s[k + 1];
        int hcur = o1 - o0;
        int rlo = o0 - 2; if (rlo < 0) rlo = 0;
        int rhi = o1 + 2; if (rhi > Sz) rhi = Sz;
        int nv = rhi - rlo;                       // 510, 512, 512, 526
        int ne = nv * Sz;

        // fused dual-map logit GEMMs -> Fg, Fa  (z<8: G-map, z>=8: A-map)
        dim3 g1(Sz / 128, (nv + 127) / 128, 16);
        gemm_f16<false><<<g1, 512, 0, stream>>>(
            x16 + (size_t)rlo * Dz, x16,
            C1f + (size_t)rlo * Dz, C2f,
            nullptr, Fg, Fa,
            nv, Sz, Dz, (long)SD, (long)SD, (long)PS, 0);

        // pair softmax -> Gsm, Asm (fp16)
        softmax2_f16<<<(ne / 4 + 255) / 256, 256, 0, stream>>>(
            Fg, Fa, Gsm, Asm, ne, (long)PS);

        // moca -> Mf (aliases Fg)
        moca_kernel<<<dim3(1, hcur, Bz), 256, 0, stream>>>(
            Gsm, Asm, w3, b3, Mf, o0, rlo, (long)PS, (long)((size_t)hcur * Sz));

        // Wz = M @ C4T^T + x -> out
        dim3 g2(Dz / 128, (hcur + 127) / 128, 8);
        gemm_f16<true><<<g2, 512, 0, stream>>>(
            Mf, C4T, Mf, C4T,
            x + (size_t)o0 * Dz, out + (size_t)o0 * Dz, out + (size_t)o0 * Dz,
            hcur, Dz, Sz, (long)((size_t)hcur * Sz), (long)SD, (long)SD, (long)SD);
    }
}